// Round 8
// baseline (215.011 us; speedup 1.0000x reference)
//
#include <hip/hip_runtime.h>
#include <math.h>

// Problem constants
#define B_    256
#define S_    196
#define DIM_  768
#define D4_   192          // DIM/4
#define POOL_ 1024
#define LEN_  8
#define TOPK_ 8

// Output layout (fp32, concatenated flat in return order)
#define RS_OFF     51118080L
#define SIM_OFF    51118081L
#define IDX_OFF    51380225L

// Workspace layout (float offsets)
#define WS_XNORM   0L          // 256*768             = 196608
#define WS_PNORMT  196608L     // 768*1024 transposed = 786432
#define WS_CANDV   983040L     // 256*32 floats (row-quarter top-8 values)
#define WS_CANDI   991232L     // 256*32 ints   (matching pool indices)

// ---------------------------------------------------------------------------
// K1: fused prep (proven). Blocks 0..255: contiguous copy + mean + l2norm.
// Blocks 256..511: prompt_key l2norm -> transposed pnormT (4 rows/block).
// ---------------------------------------------------------------------------
__global__ void __launch_bounds__(768) prep_kernel(
        const float4* __restrict__ x4,
        const float4* __restrict__ pk4,
        float4* __restrict__ out4,
        float4* __restrict__ xnorm4,
        float* __restrict__ pT) {
    __shared__ float4 part[768];
    __shared__ float  sred[192];
    __shared__ float  sscale;
    __shared__ float  wss[12];
    int t = threadIdx.x;   // 0..767
    if (blockIdx.x < B_) {
        int b = blockIdx.x;
        const float4* xr = x4 + (long)b * (S_ * D4_);          // contiguous 588 KB
        float4* ow = out4 + ((long)b * 260 + 64) * D4_;        // contiguous dest
        float4 acc = {0.f, 0.f, 0.f, 0.f};
        // 196*192 = 37632 = 49*768; (t + k*768) % 192 == t % 192
        #pragma unroll 7
        for (int k = 0; k < 49; ++k) {
            int i = t + k * 768;
            float4 v = xr[i];
            acc.x += v.x; acc.y += v.y; acc.z += v.z; acc.w += v.w;
            ow[i] = v;
        }
        part[t] = acc;
        __syncthreads();
        float4 m = {0.f, 0.f, 0.f, 0.f};
        if (t < 192) {
            float4 a = part[t], b1 = part[t + 192], c1 = part[t + 384], d1 = part[t + 576];
            m.x = (a.x + b1.x + c1.x + d1.x) / 196.f;
            m.y = (a.y + b1.y + c1.y + d1.y) / 196.f;
            m.z = (a.z + b1.z + c1.z + d1.z) / 196.f;
            m.w = (a.w + b1.w + c1.w + d1.w) / 196.f;
            sred[t] = m.x * m.x + m.y * m.y + m.z * m.z + m.w * m.w;
        }
        __syncthreads();
        if (t < 64) {
            float s2 = sred[t] + sred[t + 64] + sred[t + 128];
            #pragma unroll
            for (int off = 32; off > 0; off >>= 1) s2 += __shfl_xor(s2, off);
            if (t == 0) sscale = 1.0f / sqrtf(fmaxf(s2, 1e-12f));
        }
        __syncthreads();
        if (t < 192) {
            float sc = sscale;
            float4 o = {m.x * sc, m.y * sc, m.z * sc, m.w * sc};
            xnorm4[(long)b * D4_ + t] = o;
        }
    } else {
        int r0 = (blockIdx.x - B_) * 4;
        int g = t / 192, i = t % 192;   // group 0..3 == waves [3g,3g+2]
        int r = r0 + g;
        float4 v = pk4[(long)r * D4_ + i];
        float ss = v.x * v.x + v.y * v.y + v.z * v.z + v.w * v.w;
        #pragma unroll
        for (int off = 32; off > 0; off >>= 1) ss += __shfl_xor(ss, off);
        if ((t & 63) == 0) wss[t >> 6] = ss;
        __syncthreads();
        float tot = wss[3 * g] + wss[3 * g + 1] + wss[3 * g + 2];
        float sc = 1.0f / sqrtf(fmaxf(tot, 1e-12f));
        int d = i * 4;
        pT[(long)d       * POOL_ + r] = v.x * sc;
        pT[(long)(d + 1) * POOL_ + r] = v.y * sc;
        pT[(long)(d + 2) * POOL_ + r] = v.z * sc;
        pT[(long)(d + 3) * POOL_ + r] = v.w * sc;
    }
}

// ---------------------------------------------------------------------------
// K2: similarity (final values) + per-row-per-quarter top-8 candidates.
// grid = (64 bg, 4 pc), block = 512. Rows 4bg..4bg+3 x cols [pc*256,+256),
// full D=768 split 8-way (ds), LDS-reduced (proven round-7 math). Wave 0
// then extracts its quarter's top-8 (ties -> smallest idx) per row.
// ---------------------------------------------------------------------------
__global__ void __launch_bounds__(512) sim_cand_kernel(
        const float4* __restrict__ xnorm4,
        const float4* __restrict__ pT4,    // [768][256] float4
        float4* __restrict__ sim4,         // [256][256] float4
        float* __restrict__ cand_val,      // [256][4][8]
        int*   __restrict__ cand_idx) {    // [256][4][8]
    __shared__ float4 xs4[768];            // 12 KB
    __shared__ float4 red4[7 * 256];       // 28 KB
    int bg = blockIdx.x;     // 0..63
    int pc = blockIdx.y;     // 0..3
    int t  = threadIdx.x;    // 0..511
    int q64 = t & 63;        // col-quad within the 256-col quarter
    int ds  = t >> 6;        // 0..7 d-octant (96 d's each)
    {
        int i = t;
        xs4[i] = xnorm4[(long)(bg * 4 + i / 192) * D4_ + (i % 192)];
        i = t + 512;
        if (i < 768)
            xs4[i] = xnorm4[(long)(bg * 4 + i / 192) * D4_ + (i % 192)];
    }
    __syncthreads();
    float4 a0 = {0,0,0,0}, a1 = {0,0,0,0}, a2 = {0,0,0,0}, a3 = {0,0,0,0};
    const float4* pbase = pT4 + ((long)ds * 96) * 256 + pc * 64 + q64;
    int xq = ds * 24;
    #pragma unroll 3
    for (int q = 0; q < 24; ++q) {
        float4 xa = xs4[xq + q];
        float4 xb = xs4[192 + xq + q];
        float4 xc = xs4[384 + xq + q];
        float4 xd = xs4[576 + xq + q];
        const float* xaf = (const float*)&xa;
        const float* xbf = (const float*)&xb;
        const float* xcf = (const float*)&xc;
        const float* xdf = (const float*)&xd;
        #pragma unroll
        for (int j = 0; j < 4; ++j) {
            float4 w = pbase[(q * 4 + j) * 256];
            a0.x += xaf[j] * w.x; a0.y += xaf[j] * w.y; a0.z += xaf[j] * w.z; a0.w += xaf[j] * w.w;
            a1.x += xbf[j] * w.x; a1.y += xbf[j] * w.y; a1.z += xbf[j] * w.z; a1.w += xbf[j] * w.w;
            a2.x += xcf[j] * w.x; a2.y += xcf[j] * w.y; a2.z += xcf[j] * w.z; a2.w += xcf[j] * w.w;
            a3.x += xdf[j] * w.x; a3.y += xdf[j] * w.y; a3.z += xdf[j] * w.z; a3.w += xdf[j] * w.w;
        }
    }
    if (ds > 0) {
        int s = ds - 1;
        red4[s * 256 +        q64] = a0;
        red4[s * 256 +  64  + q64] = a1;
        red4[s * 256 + 128  + q64] = a2;
        red4[s * 256 + 192  + q64] = a3;
    }
    __syncthreads();
    if (ds == 0) {   // wave 0 exactly (t = q64 in [0,64))
        #pragma unroll
        for (int s = 0; s < 7; ++s) {
            float4 b0 = red4[s * 256 +       q64];
            float4 b1 = red4[s * 256 +  64 + q64];
            float4 b2 = red4[s * 256 + 128 + q64];
            float4 b3 = red4[s * 256 + 192 + q64];
            a0.x += b0.x; a0.y += b0.y; a0.z += b0.z; a0.w += b0.w;
            a1.x += b1.x; a1.y += b1.y; a1.z += b1.z; a1.w += b1.w;
            a2.x += b2.x; a2.y += b2.y; a2.z += b2.z; a2.w += b2.w;
            a3.x += b3.x; a3.y += b3.y; a3.z += b3.z; a3.w += b3.w;
        }
        long base = ((long)(bg * 4)) * 256 + pc * 64 + q64;
        sim4[base]       = a0;
        sim4[base + 256] = a1;
        sim4[base + 512] = a2;
        sim4[base + 768] = a3;

        // per-row quarter top-8 candidates (lane q64 holds cols base_idx..+3)
        int lane = q64;
        int base_idx = pc * 256 + lane * 4;
        #pragma unroll
        for (int r = 0; r < 4; ++r) {
            float4 av = (r == 0) ? a0 : (r == 1) ? a1 : (r == 2) ? a2 : a3;
            float v0 = av.x, v1 = av.y, v2 = av.z, v3 = av.w;
            int row = bg * 4 + r;
            for (int it = 0; it < TOPK_; ++it) {
                // local argmax over 4 (keep-first => smallest idx)
                float bv = v0; int bj = 0;
                if (v1 > bv) { bv = v1; bj = 1; }
                if (v2 > bv) { bv = v2; bj = 2; }
                if (v3 > bv) { bv = v3; bj = 3; }
                int bi = base_idx + bj;
                #pragma unroll
                for (int off = 32; off > 0; off >>= 1) {
                    float ov = __shfl_xor(bv, off);
                    int   oi = __shfl_xor(bi, off);
                    if (ov > bv || (ov == bv && oi < bi)) { bv = ov; bi = oi; }
                }
                if (lane == 0) {
                    cand_val[row * 32 + pc * 8 + it] = bv;
                    cand_idx[row * 32 + pc * 8 + it] = bi;
                }
                bool mine = (((bi >> 2) & 63) == lane);
                int  mj   = bi & 3;
                v0 = (mine && mj == 0) ? -INFINITY : v0;
                v1 = (mine && mj == 1) ? -INFINITY : v1;
                v2 = (mine && mj == 2) ? -INFINITY : v2;
                v3 = (mine && mj == 3) ? -INFINITY : v3;
            }
        }
    }
}

// ---------------------------------------------------------------------------
// K3: final node. 256 blocks x 1024 threads, block b -> batch row b.
// Every block redundantly: merge candidates -> row winners -> LDS histogram
// -> count top-8 (ties -> smallest pool id) -> majs. Block 0 also writes
// idx output + reduce_sim. Then all blocks gather their head slice.
// Deterministic: identical inputs + order-independent int ops in all blocks.
// ---------------------------------------------------------------------------
__global__ void __launch_bounds__(1024) final_kernel(
        const float* __restrict__ cand_val,
        const int*   __restrict__ cand_idx,
        const float* __restrict__ sim,
        const float4* __restrict__ prompt4,
        float4* __restrict__ out4,
        float*  __restrict__ idx_out,
        float*  __restrict__ rs_out) {
    __shared__ int   winners[B_ * TOPK_];   // 8 KB
    __shared__ int   hist[POOL_];           // 4 KB
    __shared__ int   majs[TOPK_];
    __shared__ float redc[256];
    const int b = blockIdx.x;
    const int t = threadIdx.x;
    const int wv = t >> 6, lane = t & 63;   // 16 waves

    // ----- merge: wave wv handles rows wv*16 .. wv*16+15 -----
    #pragma unroll 2
    for (int i = 0; i < 16; ++i) {
        int r = wv * 16 + i;
        float cv; int ci;
        if (lane < 32) {
            cv = cand_val[r * 32 + lane];
            ci = cand_idx[r * 32 + lane];
        } else {
            cv = -INFINITY;
            ci = 0x7fffffff;
        }
        for (int it = 0; it < TOPK_; ++it) {
            float bv = cv; int bi = ci;
            #pragma unroll
            for (int off = 32; off > 0; off >>= 1) {
                float ov = __shfl_xor(bv, off);
                int   oi = __shfl_xor(bi, off);
                if (ov > bv || (ov == bv && oi < bi)) { bv = ov; bi = oi; }
            }
            if (lane == 0) winners[r * TOPK_ + it] = bi;
            if (ci == bi) cv = -INFINITY;   // idx unique -> exactly one lane
        }
    }
    // ----- histogram -----
    hist[t] = 0;
    __syncthreads();
    atomicAdd(&hist[winners[t]], 1);
    atomicAdd(&hist[winners[t + 1024]], 1);
    __syncthreads();
    // ----- top-8 of counts (wave 0; ties -> smallest pool id) -----
    if (t < 64) {
        int v[16];
        #pragma unroll
        for (int j = 0; j < 16; ++j) v[j] = hist[lane + j * 64];
        for (int it = 0; it < TOPK_; ++it) {
            int bv = v[0];
            int bi = lane;
            #pragma unroll
            for (int j = 1; j < 16; ++j) {
                if (v[j] > bv) { bv = v[j]; bi = lane + j * 64; }
            }
            #pragma unroll
            for (int off = 32; off > 0; off >>= 1) {
                int ov = __shfl_xor(bv, off);
                int oi = __shfl_xor(bi, off);
                if (ov > bv || (ov == bv && oi < bi)) { bv = ov; bi = oi; }
            }
            if (lane == 0) majs[it] = bi;
            if ((bi & 63) == lane) v[bi >> 6] = -1;
        }
    }
    __syncthreads();
    // ----- block 0 extras: idx output + reduce_sim -----
    if (b == 0) {
        for (int i = t; i < B_ * TOPK_; i += 1024) idx_out[i] = (float)majs[i & 7];
        if (t < 256) {
            float s = 0.f;
            const float* r = sim + (long)t * POOL_;
            #pragma unroll
            for (int k = 0; k < TOPK_; ++k) s += r[majs[k]];
            redc[t] = s;
        }
        __syncthreads();
        for (int off = 128; off > 0; off >>= 1) {
            if (t < off) redc[t] += redc[t + off];
            __syncthreads();
        }
        if (t == 0) *rs_out = redc[0] / (float)B_;
    }
    // ----- gather: contiguous 768 KB head slice of batch row b -----
    {
        float4* dst = out4 + (long)b * 260 * D4_;   // 64*192 = 12288 float4
        #pragma unroll 4
        for (int k = 0; k < 12; ++k) {
            int i = t + k * 1024;
            int kl = i / 192;
            int d4 = i % 192;
            int pid = majs[kl >> 3];
            dst[i] = prompt4[((long)pid * LEN_ + (kl & 7)) * D4_ + d4];
        }
    }
}

// ---------------------------------------------------------------------------
extern "C" void kernel_launch(void* const* d_in, const int* in_sizes, int n_in,
                              void* d_out, int out_size, void* d_ws, size_t ws_size,
                              hipStream_t stream) {
    const float4* x4      = (const float4*)d_in[0];
    const float4* prompt4 = (const float4*)d_in[1];
    const float4* pk4     = (const float4*)d_in[2];
    float* out = (float*)d_out;
    float* ws  = (float*)d_ws;

    float4* out4     = (float4*)out;
    float4* xnorm4   = (float4*)(ws + WS_XNORM);
    float*  pT       = ws + WS_PNORMT;
    float*  cand_val = ws + WS_CANDV;
    int*    cand_idx = (int*)(ws + WS_CANDI);
    float*  out_rs   = out + RS_OFF;
    float*  out_sim  = out + SIM_OFF;
    float*  out_idx  = out + IDX_OFF;

    // Node 1: prep (copy+mean+l2norm, pk l2normT)
    prep_kernel<<<512, 768, 0, stream>>>(x4, pk4, out4, xnorm4, pT);
    // Node 2: similarity + per-quarter top-8 candidates
    dim3 sg(64, 4);
    sim_cand_kernel<<<sg, 512, 0, stream>>>(xnorm4, (const float4*)pT,
                                            (float4*)out_sim, cand_val, cand_idx);
    // Node 3: merge + consensus (redundant per block) + idx/reduce_sim + gather
    final_kernel<<<B_, 1024, 0, stream>>>(cand_val, cand_idx, out_sim, prompt4,
                                          out4, out_idx, out_rs);
}

// Round 9
// 119.068 us; speedup vs baseline: 1.8058x; 1.8058x over previous
//
#include <hip/hip_runtime.h>
#include <math.h>

// Problem constants
#define B_    256
#define S_    196
#define DIM_  768
#define D4_   192          // DIM/4
#define POOL_ 1024
#define LEN_  8
#define TOPK_ 8

// Output layout (fp32, concatenated flat in return order)
#define RS_OFF     51118080L
#define SIM_OFF    51118081L
#define IDX_OFF    51380225L

// Workspace layout (float offsets)  — same as proven round-4 layout
#define WS_XNORM   0L          // 256*768             = 196608
#define WS_PNORMT  196608L     // 768*1024 transposed = 786432
#define WS_PART    983040L     // 4*256*1024 partials = 1048576
#define WS_ROWIDS  2031616L    // 256*8 int

// ---------------------------------------------------------------------------
// K1: fused prep (byte-identical to round-4's proven kernel).
// Blocks 0..255: per-batch-row contiguous copy + mean + l2norm.
// Blocks 256..511: prompt_key l2norm -> transposed pnormT (4 rows/block).
// ---------------------------------------------------------------------------
__global__ void __launch_bounds__(768) prep_kernel(
        const float4* __restrict__ x4,
        const float4* __restrict__ pk4,
        float4* __restrict__ out4,
        float4* __restrict__ xnorm4,
        float* __restrict__ pT) {
    __shared__ float4 part[768];
    __shared__ float  sred[192];
    __shared__ float  sscale;
    __shared__ float  wss[12];
    int t = threadIdx.x;   // 0..767
    if (blockIdx.x < B_) {
        int b = blockIdx.x;
        const float4* xr = x4 + (long)b * (S_ * D4_);          // contiguous 588 KB
        float4* ow = out4 + ((long)b * 260 + 64) * D4_;        // contiguous dest
        float4 acc = {0.f, 0.f, 0.f, 0.f};
        // 196*192 = 37632 = 49*768; (t + k*768) % 192 == t % 192
        #pragma unroll 7
        for (int k = 0; k < 49; ++k) {
            int i = t + k * 768;
            float4 v = xr[i];
            acc.x += v.x; acc.y += v.y; acc.z += v.z; acc.w += v.w;
            ow[i] = v;
        }
        part[t] = acc;
        __syncthreads();
        float4 m = {0.f, 0.f, 0.f, 0.f};
        if (t < 192) {
            float4 a = part[t], b1 = part[t + 192], c1 = part[t + 384], d1 = part[t + 576];
            m.x = (a.x + b1.x + c1.x + d1.x) / 196.f;
            m.y = (a.y + b1.y + c1.y + d1.y) / 196.f;
            m.z = (a.z + b1.z + c1.z + d1.z) / 196.f;
            m.w = (a.w + b1.w + c1.w + d1.w) / 196.f;
            sred[t] = m.x * m.x + m.y * m.y + m.z * m.z + m.w * m.w;
        }
        __syncthreads();
        if (t < 64) {
            float s2 = sred[t] + sred[t + 64] + sred[t + 128];
            #pragma unroll
            for (int off = 32; off > 0; off >>= 1) s2 += __shfl_xor(s2, off);
            if (t == 0) sscale = 1.0f / sqrtf(fmaxf(s2, 1e-12f));
        }
        __syncthreads();
        if (t < 192) {
            float sc = sscale;
            float4 o = {m.x * sc, m.y * sc, m.z * sc, m.w * sc};
            xnorm4[(long)b * D4_ + t] = o;
        }
    } else {
        int r0 = (blockIdx.x - B_) * 4;
        int g = t / 192, i = t % 192;   // group 0..3 == waves [3g,3g+2]
        int r = r0 + g;
        float4 v = pk4[(long)r * D4_ + i];
        float ss = v.x * v.x + v.y * v.y + v.z * v.z + v.w * v.w;
        #pragma unroll
        for (int off = 32; off > 0; off >>= 1) ss += __shfl_xor(ss, off);
        if ((t & 63) == 0) wss[t >> 6] = ss;
        __syncthreads();
        float tot = wss[3 * g] + wss[3 * g + 1] + wss[3 * g + 2];
        float sc = 1.0f / sqrtf(fmaxf(tot, 1e-12f));
        int d = i * 4;
        pT[(long)d       * POOL_ + r] = v.x * sc;
        pT[(long)(d + 1) * POOL_ + r] = v.y * sc;
        pT[(long)(d + 2) * POOL_ + r] = v.z * sc;
        pT[(long)(d + 3) * POOL_ + r] = v.w * sc;
    }
}

// ---------------------------------------------------------------------------
// K2: similarity partials (byte-identical to round-4). grid = (64 bg, 4 dc),
// block = 512. Thread owns 4 rows x 4 consecutive cols; 2-way d-split.
// ---------------------------------------------------------------------------
__global__ void __launch_bounds__(512) simpart_kernel(
        const float4* __restrict__ xnorm4,
        const float4* __restrict__ pT4,    // [768][256] float4
        float4* __restrict__ part4) {      // [4dc][256row][256colquad]
    __shared__ float4 xs4[4 * 48];         // [row][48] f4 = 192 d's chunk
    __shared__ float4 red4[4 * 256];       // [row][colquad]
    int bg = blockIdx.x;     // 0..63
    int dc = blockIdx.y;     // 0..3
    int t  = threadIdx.x;    // 0..511
    int p4 = t & 255;        // colquad: cols 4*p4..4*p4+3
    int ds = t >> 8;         // 0/1 half of the d-chunk
    if (t < 192) {
        int r = t / 48, q = t % 48;
        xs4[r * 48 + q] = xnorm4[(long)(bg * 4 + r) * D4_ + dc * 48 + q];
    }
    __syncthreads();
    float4 a0 = {0,0,0,0}, a1 = {0,0,0,0}, a2 = {0,0,0,0}, a3 = {0,0,0,0};
    int qbase = ds * 24;
    const float4* pbase = pT4 + ((long)dc * 192 + ds * 96) * 256 + p4;
    #pragma unroll 2
    for (int q = 0; q < 24; ++q) {
        float4 xa = xs4[qbase + q];
        float4 xb = xs4[48 + qbase + q];
        float4 xc = xs4[96 + qbase + q];
        float4 xd = xs4[144 + qbase + q];
        const float* xaf = (const float*)&xa;
        const float* xbf = (const float*)&xb;
        const float* xcf = (const float*)&xc;
        const float* xdf = (const float*)&xd;
        #pragma unroll
        for (int j = 0; j < 4; ++j) {
            float4 w = pbase[(q * 4 + j) * 256];
            a0.x += xaf[j] * w.x; a0.y += xaf[j] * w.y; a0.z += xaf[j] * w.z; a0.w += xaf[j] * w.w;
            a1.x += xbf[j] * w.x; a1.y += xbf[j] * w.y; a1.z += xbf[j] * w.z; a1.w += xbf[j] * w.w;
            a2.x += xcf[j] * w.x; a2.y += xcf[j] * w.y; a2.z += xcf[j] * w.z; a2.w += xcf[j] * w.w;
            a3.x += xdf[j] * w.x; a3.y += xdf[j] * w.y; a3.z += xdf[j] * w.z; a3.w += xdf[j] * w.w;
        }
    }
    if (ds == 1) {
        red4[p4]       = a0;
        red4[256 + p4] = a1;
        red4[512 + p4] = a2;
        red4[768 + p4] = a3;
    }
    __syncthreads();
    if (ds == 0) {
        float4 b0 = red4[p4], b1 = red4[256 + p4], b2 = red4[512 + p4], b3 = red4[768 + p4];
        a0.x += b0.x; a0.y += b0.y; a0.z += b0.z; a0.w += b0.w;
        a1.x += b1.x; a1.y += b1.y; a1.z += b1.z; a1.w += b1.w;
        a2.x += b2.x; a2.y += b2.y; a2.z += b2.z; a2.w += b2.w;
        a3.x += b3.x; a3.y += b3.y; a3.z += b3.z; a3.w += b3.w;
        long base = ((long)dc * 256 + bg * 4) * 256 + p4;
        part4[base]       = a0;
        part4[base + 256] = a1;
        part4[base + 512] = a2;
        part4[base + 768] = a3;
    }
}

// ---------------------------------------------------------------------------
// K3: sum 4 partials per row -> sim; per-row top-8 (ties -> smallest index).
// grid = 256 (one wave per row). Byte-identical to round-4.
// ---------------------------------------------------------------------------
__global__ void topk_sum_kernel(const float* __restrict__ part,
                                float* __restrict__ sim,
                                int* __restrict__ row_ids) {
    int row  = blockIdx.x;
    int lane = threadIdx.x;      // 64
    float v[16];
    #pragma unroll
    for (int j = 0; j < 16; ++j) {
        int p = lane + j * 64;
        float s = part[(long)row * POOL_ + p]
                + part[(long)(256 + row) * POOL_ + p]
                + part[(long)(512 + row) * POOL_ + p]
                + part[(long)(768 + row) * POOL_ + p];
        v[j] = s;
        sim[(long)row * POOL_ + p] = s;
    }
    for (int it = 0; it < TOPK_; ++it) {
        float bv = v[0];
        int   bi = lane;
        #pragma unroll
        for (int j = 1; j < 16; ++j) {
            if (v[j] > bv) { bv = v[j]; bi = lane + j * 64; }  // keep-first => smallest idx
        }
        #pragma unroll
        for (int off = 32; off > 0; off >>= 1) {
            float ov = __shfl_xor(bv, off);
            int   oi = __shfl_xor(bi, off);
            if (ov > bv || (ov == bv && oi < bi)) { bv = ov; bi = oi; }
        }
        if ((bi & 63) == lane) v[bi >> 6] = -INFINITY;
        if (lane == 0) row_ids[row * TOPK_ + it] = bi;
    }
}

// ---------------------------------------------------------------------------
// K4: gather + LIGHT redundant consensus. 256 blocks x 1024 threads,
// block b -> batch row b. Each block: LDS histogram of the 2048 row ids
// (2 LDS atomics/thread) -> ONE single-wave count-top-8 (ties -> smallest
// pool id) -> majs (identical in every block: integer, order-independent).
// Block 0 additionally writes idx output + reduce_sim. Then all blocks
// stream their contiguous 196 KB head slice.
// ---------------------------------------------------------------------------
__global__ void __launch_bounds__(1024) gather_consensus_kernel(
        const int*    __restrict__ row_ids,
        const float*  __restrict__ sim,
        const float4* __restrict__ prompt4,
        float4* __restrict__ out4,
        float*  __restrict__ idx_out,
        float*  __restrict__ rs_out) {
    __shared__ int   hist[POOL_];
    __shared__ int   majs[TOPK_];
    __shared__ float redc[256];
    const int b = blockIdx.x;
    const int t = threadIdx.x;

    // ----- histogram (all blocks, redundant, cheap) -----
    hist[t] = 0;
    __syncthreads();
    atomicAdd(&hist[row_ids[t]], 1);
    atomicAdd(&hist[row_ids[t + 1024]], 1);
    __syncthreads();

    // ----- count top-8 (wave 0 only; ties -> smallest pool id) -----
    if (t < 64) {
        int lane = t;
        int v[16];
        #pragma unroll
        for (int j = 0; j < 16; ++j) v[j] = hist[lane + j * 64];
        for (int it = 0; it < TOPK_; ++it) {
            int bv = v[0];
            int bi = lane;
            #pragma unroll
            for (int j = 1; j < 16; ++j) {
                if (v[j] > bv) { bv = v[j]; bi = lane + j * 64; }
            }
            #pragma unroll
            for (int off = 32; off > 0; off >>= 1) {
                int ov = __shfl_xor(bv, off);
                int oi = __shfl_xor(bi, off);
                if (ov > bv || (ov == bv && oi < bi)) { bv = ov; bi = oi; }
            }
            if (lane == 0) majs[it] = bi;
            if ((bi & 63) == lane) v[bi >> 6] = -1;
        }
    }
    __syncthreads();

    // ----- block 0 extras: idx output + reduce_sim -----
    if (b == 0) {
        for (int i = t; i < B_ * TOPK_; i += 1024) idx_out[i] = (float)majs[i & 7];
        if (t < 256) {
            float s = 0.f;
            const float* r = sim + (long)t * POOL_;
            #pragma unroll
            for (int k = 0; k < TOPK_; ++k) s += r[majs[k]];
            redc[t] = s;
        }
        __syncthreads();
        for (int off = 128; off > 0; off >>= 1) {
            if (t < off) redc[t] += redc[t + off];
            __syncthreads();
        }
        if (t == 0) *rs_out = redc[0] / (float)B_;
    }

    // ----- gather: contiguous head slice of batch row b -----
    {
        float4* dst = out4 + (long)b * 260 * D4_;   // 64*192 = 12288 float4
        #pragma unroll 4
        for (int k = 0; k < 12; ++k) {
            int i = t + k * 1024;
            int kl = i / 192;
            int d4 = i % 192;
            int pid = majs[kl >> 3];
            dst[i] = prompt4[((long)pid * LEN_ + (kl & 7)) * D4_ + d4];
        }
    }
}

// ---------------------------------------------------------------------------
extern "C" void kernel_launch(void* const* d_in, const int* in_sizes, int n_in,
                              void* d_out, int out_size, void* d_ws, size_t ws_size,
                              hipStream_t stream) {
    const float4* x4      = (const float4*)d_in[0];
    const float4* prompt4 = (const float4*)d_in[1];
    const float4* pk4     = (const float4*)d_in[2];
    float* out = (float*)d_out;
    float* ws  = (float*)d_ws;

    float4* out4    = (float4*)out;
    float4* xnorm4  = (float4*)(ws + WS_XNORM);
    float*  pT      = ws + WS_PNORMT;
    float4* part4   = (float4*)(ws + WS_PART);
    int*    row_ids = (int*)(ws + WS_ROWIDS);
    float*  out_rs  = out + RS_OFF;
    float*  out_sim = out + SIM_OFF;
    float*  out_idx = out + IDX_OFF;

    // Node 1: prep (copy+mean+l2norm, pk l2normT)          [proven R4]
    prep_kernel<<<512, 768, 0, stream>>>(x4, pk4, out4, xnorm4, pT);
    // Node 2: similarity partials over the whole chip       [proven R4]
    dim3 sgrid(64, 4);
    simpart_kernel<<<sgrid, 512, 0, stream>>>(xnorm4, (const float4*)pT, part4);
    // Node 3: sum partials + per-row top-8                  [proven R4]
    topk_sum_kernel<<<B_, 64, 0, stream>>>((const float*)part4, out_sim, row_ids);
    // Node 4: light redundant consensus + idx/reduce_sim + gather
    gather_consensus_kernel<<<B_, 1024, 0, stream>>>(row_ids, out_sim, prompt4,
                                                     out4, out_idx, out_rs);
}